// Round 6
// baseline (322.745 us; speedup 1.0000x reference)
//
#include <hip/hip_runtime.h>

// DivergenceFreeMLP — all-f32 implementation.
// out = a2 @ Wp3 - c1 @ Wp1 + bp, where masks m1,m2 come from exact f32 h1,h2.
//   Wpc[192][512] = [W3^T Wp^T ; W1 Wp^T]  (precomputed per launch, 201M MACs)
//   A_T[192][8192] = [a2 ; -m1*c1] stored transposed (coalesced both sides)
// Big GEMMs use wave-uniform scalar-operand FMAs (s_load + v_fmac v,s,v).
// k_h1 is split-K-2 (two partial buffers, summed in k_mid) so all 256 CUs fill.
// R4 fix (re-audited, unbenched due to infra): k_wpc K-chunk processed as
// 4 sub-chunks of 64 to match the stride-68 LDS tiles.

#define B_N   8192
#define D_N   2048
#define H1_N  128
#define H2_N  64
#define OUT_N 512

// workspace layout (float offsets), peak 3,801,088 floats = 14.5 MiB
#define WS_W1R  0         // [128]
#define WS_W3C  128       // [64]
#define WS_W2T  256       // [128][64] -> 8448
#define WS_WPC  16384     // [192][512] -> 114688
#define WS_WPCP 114688    // [8][192][512] -> 901120 (dead after k_wpc_red)
#define WS_H1PA 131072    // [128][8192] -> 1179648 (aliases WPCP; lifetime disjoint)
#define WS_H1PB 1179648   // [128][8192] -> 2228224
#define WS_AT   2228224   // [192][8192] -> 3801088

__global__ __launch_bounds__(256) void k_pre(const float* __restrict__ W1,
                                             const float* __restrict__ W2,
                                             const float* __restrict__ W3,
                                             float* __restrict__ ws) {
  int b = blockIdx.x, t = threadIdx.x;
  __shared__ float red[256];
  if (b < 128) {                       // w1r[b] = sum_d W1[b][d]
    float s = 0.f;
    const float* row = W1 + (size_t)b * D_N;
    for (int i = t; i < D_N; i += 256) s += row[i];
    red[t] = s; __syncthreads();
    for (int off = 128; off > 0; off >>= 1) { if (t < off) red[t] += red[t + off]; __syncthreads(); }
    if (t == 0) ws[WS_W1R + b] = red[0];
  } else if (b < 192) {                // w3c[c] = sum_d W3[d][c]
    int c = b - 128;
    float s = 0.f;
    for (int d = t; d < D_N; d += 256) s += W3[(size_t)d * H2_N + c];
    red[t] = s; __syncthreads();
    for (int off = 128; off > 0; off >>= 1) { if (t < off) red[t] += red[t + off]; __syncthreads(); }
    if (t == 0) ws[WS_W3C + c] = red[0];
  } else {                             // W2T[j][u] = W2[u][j]
    int flat = (b - 192) * 256 + t;    // 0..8191
    int j = flat >> 6, u = flat & 63;
    ws[WS_W2T + j * H2_N + u] = W2[u * H1_N + j];
  }
}

// Wpc partials: block = (rt 0..5, ot 0..7, kc 0..7); tile 32r x 64o.
// K-chunk 256 processed as 4 sub-chunks of 64 (LDS tiles stride 68).
__global__ __launch_bounds__(128) void k_wpc(const float* __restrict__ W1,
                                             const float* __restrict__ W3,
                                             const float* __restrict__ Wp,
                                             float* __restrict__ ws) {
  int b = blockIdx.x, t = threadIdx.x;
  int rt = b % 6, ot = (b / 6) % 8, kc = b / 48;
  __shared__ float As[32 * 68];        // [r][k] stride 68, k-sub 64
  __shared__ float Bs[64 * 68];        // [o][k] stride 68
  int rg = t >> 4, og = t & 15;        // 8 x 16 thread grid, tile 4r x 4o
  float acc[4][4];
  #pragma unroll
  for (int i = 0; i < 4; ++i)
    #pragma unroll
    for (int j = 0; j < 4; ++j) acc[i][j] = 0.f;
  for (int sub = 0; sub < 4; ++sub) {
    int k0 = kc * 256 + sub * 64;
    __syncthreads();                   // protect prev-iter reads
    if (rt < 2) {  // rows r<64: A[r][k] = W3[k0+k][rt*32+r] (strided columns)
      #pragma unroll
      for (int i = 0; i < 4; ++i) {
        int flat = i * 128 + t;        // 512 float4: 8 rq x 64 kl
        int rq = flat & 7, kl = flat >> 3;
        const float4 v = *reinterpret_cast<const float4*>(W3 + (size_t)(k0 + kl) * H2_N + rt * 32 + rq * 4);
        As[(rq * 4 + 0) * 68 + kl] = v.x;
        As[(rq * 4 + 1) * 68 + kl] = v.y;
        As[(rq * 4 + 2) * 68 + kl] = v.z;
        As[(rq * 4 + 3) * 68 + kl] = v.w;
      }
    } else {       // rows r>=64: A[r][k] = W1[rt*32+r-64][k0+k]
      #pragma unroll
      for (int i = 0; i < 4; ++i) {
        int flat = i * 128 + t;        // 512 float4: 16 kq x 32 rl
        int kq = flat & 15, rl = flat >> 4;
        const float4 v = *reinterpret_cast<const float4*>(W1 + (size_t)(rt * 32 + rl - 64) * D_N + k0 + kq * 4);
        *reinterpret_cast<float4*>(&As[rl * 68 + kq * 4]) = v;
      }
    }
    #pragma unroll
    for (int i = 0; i < 8; ++i) {      // B[o][k] = Wp[ot*64+o][k0+k]
      int flat = i * 128 + t;          // 1024 float4: 16 kq x 64 ol
      int kq = flat & 15, ol = flat >> 4;
      const float4 v = *reinterpret_cast<const float4*>(Wp + (size_t)(ot * 64 + ol) * D_N + k0 + kq * 4);
      *reinterpret_cast<float4*>(&Bs[ol * 68 + kq * 4]) = v;
    }
    __syncthreads();
    for (int k = 0; k < 64; k += 4) {
      float4 a[4], bb[4];
      #pragma unroll
      for (int i = 0; i < 4; ++i) a[i] = *reinterpret_cast<const float4*>(&As[(rg * 4 + i) * 68 + k]);
      #pragma unroll
      for (int j = 0; j < 4; ++j) bb[j] = *reinterpret_cast<const float4*>(&Bs[(og * 4 + j) * 68 + k]);
      #pragma unroll
      for (int i = 0; i < 4; ++i)
        #pragma unroll
        for (int j = 0; j < 4; ++j) {
          acc[i][j] = fmaf(a[i].x, bb[j].x, acc[i][j]);
          acc[i][j] = fmaf(a[i].y, bb[j].y, acc[i][j]);
          acc[i][j] = fmaf(a[i].z, bb[j].z, acc[i][j]);
          acc[i][j] = fmaf(a[i].w, bb[j].w, acc[i][j]);
        }
    }
  }
  float* P = ws + WS_WPCP + (size_t)kc * (192 * 512);
  #pragma unroll
  for (int i = 0; i < 4; ++i) {
    int r = rt * 32 + rg * 4 + i;
    #pragma unroll
    for (int j = 0; j < 4; ++j)
      P[r * 512 + ot * 64 + og * 4 + j] = acc[i][j];
  }
}

__global__ __launch_bounds__(256) void k_wpc_red(float* __restrict__ ws) {
  int idx = (blockIdx.x * 256 + threadIdx.x) * 4;  // 96 blocks -> 98304 floats
  float4 s = make_float4(0.f, 0.f, 0.f, 0.f);
  #pragma unroll
  for (int p = 0; p < 8; ++p) {
    const float4 v = *reinterpret_cast<const float4*>(ws + WS_WPCP + (size_t)p * (192 * 512) + idx);
    s.x += v.x; s.y += v.y; s.z += v.z; s.w += v.w;
  }
  *reinterpret_cast<float4*>(ws + WS_WPC + idx) = s;
}

// h1 partial: block = (s-tile 0..127) x (k-half 0..1); 512 thr = 8 waves x 16 u.
// Writes PA (kh=0) / PB (kh=1); k_mid sums them. x read exactly once overall.
// K-chunk 128 keeps LDS at 33.3 KB; x staged transposed [k][65]; W1 via s_load.
__global__ __launch_bounds__(512) void k_h1(const float* __restrict__ x,
                                            const float* __restrict__ W1,
                                            float* __restrict__ ws) {
  __shared__ float xs[128 * 65];       // 33.3 KB
  int b = blockIdx.x;                  // 256 blocks
  int st = b >> 1, kh = b & 1;
  int s0 = st * 64;
  int t = threadIdx.x;
  int lane = t & 63;
  int wv = __builtin_amdgcn_readfirstlane(t >> 6);  // uniform wave id 0..7
  int u0 = wv * 16;
  float acc[16];
  #pragma unroll
  for (int i = 0; i < 16; ++i) acc[i] = 0.f;
  for (int cc = 0; cc < 8; ++cc) {
    int kc = kh * 1024 + cc * 128;
    __syncthreads();
    #pragma unroll
    for (int r = 0; r < 4; ++r) {      // stage 64 samples x 128 k, transposed
      int flat = r * 512 + t;          // bits[3:0]=kq_lo, [9:4]=s, [10]=kq_hi
      int kq = (flat & 15) | ((flat >> 10) << 4);
      int s  = (flat >> 4) & 63;
      const float4 v = *reinterpret_cast<const float4*>(x + (size_t)(s0 + s) * D_N + kc + kq * 4);
      xs[(kq * 4 + 0) * 65 + s] = v.x;
      xs[(kq * 4 + 1) * 65 + s] = v.y;
      xs[(kq * 4 + 2) * 65 + s] = v.z;
      xs[(kq * 4 + 3) * 65 + s] = v.w;
    }
    __syncthreads();
    const float* wbase = W1 + (size_t)u0 * D_N + kc;
    for (int k4 = 0; k4 < 128; k4 += 4) {
      float a0 = xs[(k4 + 0) * 65 + lane];
      float a1 = xs[(k4 + 1) * 65 + lane];
      float a2 = xs[(k4 + 2) * 65 + lane];
      float a3 = xs[(k4 + 3) * 65 + lane];
      #pragma unroll
      for (int uu = 0; uu < 16; ++uu) {
        const float* wr = wbase + (size_t)uu * D_N + k4;  // uniform -> s_load_dwordx4
        float c = acc[uu];
        c = fmaf(wr[0], a0, c);
        c = fmaf(wr[1], a1, c);
        c = fmaf(wr[2], a2, c);
        c = fmaf(wr[3], a3, c);
        acc[uu] = c;
      }
    }
  }
  float* hp = ws + (kh ? WS_H1PB : WS_H1PA);
  #pragma unroll
  for (int uu = 0; uu < 16; ++uu)
    hp[(size_t)(u0 + uu) * B_N + s0 + lane] = acc[uu];
}

// Fused mid stage: phase 1 computes h2, a2 (A_T rows 0..63) and sb=m2*w3c (LDS);
// phase 2 computes c1 and A_T rows 64..191 = -m1*c1. h1 = PA + PB + b1.
__global__ __launch_bounds__(512) void k_mid(const float* __restrict__ b1,
                                             const float* __restrict__ b2,
                                             const float* __restrict__ W2,
                                             float* __restrict__ ws) {
  __shared__ float hs[128 * 65];       // h1 + b1, 33.3 KB
  __shared__ float sb[64 * 65];        // m2*w3c,  16.6 KB
  int s0 = blockIdx.x * 64;            // 128 blocks
  int t = threadIdx.x;
  int lane = t & 63;
  int wv = __builtin_amdgcn_readfirstlane(t >> 6);  // 0..7
  const float* PA = ws + WS_H1PA;
  const float* PB = ws + WS_H1PB;
  const float* W2T = ws + WS_W2T;
  const float* w1r = ws + WS_W1R;
  const float* w3c = ws + WS_W3C;
  float* A_T = ws + WS_AT;
  // stage h1+b1: wave wv loads rows wv*16 .. wv*16+15
  #pragma unroll
  for (int jj = 0; jj < 16; ++jj) {
    int j = wv * 16 + jj;
    hs[j * 65 + lane] = PA[(size_t)j * B_N + s0 + lane]
                      + PB[(size_t)j * B_N + s0 + lane] + b1[j];
  }
  __syncthreads();
  // phase 1: wave wv owns u0 = wv*8 (8 units)
  {
    int u0 = wv * 8;
    float h2a[8], ta[8];
    #pragma unroll
    for (int i = 0; i < 8; ++i) { h2a[i] = b2[u0 + i]; ta[i] = 0.f; }
    for (int j = 0; j < H1_N; ++j) {
      float h = hs[j * 65 + lane];
      float g = fmaxf(h, 0.f);
      float a = (h > 0.f) ? w1r[j] : 0.f;
      const float* w2row = W2T + j * H2_N + u0;     // uniform -> s_load
      #pragma unroll
      for (int uu = 0; uu < 8; ++uu) {
        h2a[uu] = fmaf(w2row[uu], g, h2a[uu]);
        ta[uu]  = fmaf(w2row[uu], a, ta[uu]);
      }
    }
    #pragma unroll
    for (int uu = 0; uu < 8; ++uu) {
      bool m2 = h2a[uu] > 0.f;
      A_T[(size_t)(u0 + uu) * B_N + s0 + lane] = m2 ? ta[uu] : 0.f;
      sb[(u0 + uu) * 65 + lane] = m2 ? w3c[u0 + uu] : 0.f;
    }
  }
  __syncthreads();
  // phase 2: wave wv owns j0 = wv*16 (16 units)
  {
    int j0 = wv * 16;
    float c[16];
    #pragma unroll
    for (int i = 0; i < 16; ++i) c[i] = 0.f;
    for (int u = 0; u < H2_N; ++u) {
      float sv = sb[u * 65 + lane];
      const float* w2row = W2 + u * H1_N + j0;      // uniform -> s_load
      #pragma unroll
      for (int jj = 0; jj < 16; ++jj)
        c[jj] = fmaf(w2row[jj], sv, c[jj]);
    }
    #pragma unroll
    for (int jj = 0; jj < 16; ++jj) {
      float h = hs[(j0 + jj) * 65 + lane];
      A_T[(size_t)(64 + j0 + jj) * B_N + s0 + lane] = (h > 0.f) ? -c[jj] : 0.f;
    }
  }
}

// out[s][o] = bp[o] + sum_{k<192} A_T[k][s] * Wpc[k][o]
// block = 512 thr (8 waves x 16 samples = 128 samples), 64 o-cols; Wpc in LDS.
// grid 512 = 64 st8 x 8 ow -> exactly one residency round at 3 blocks/CU.
__global__ __launch_bounds__(512) void k_out2(const float* __restrict__ bp,
                                              const float* __restrict__ ws,
                                              float* __restrict__ out) {
  __shared__ float wp[192 * 64];       // 48 KB
  int b = blockIdx.x;                  // 512 = 64 st8 x 8 ow
  int ow = b & 7, st8 = b >> 3;
  int t = threadIdx.x;
  int lane = t & 63;
  int wv = __builtin_amdgcn_readfirstlane(t >> 6);  // 0..7
  int s0 = st8 * 128 + wv * 16;
  int o = ow * 64 + lane;
  const float* Wpc = ws + WS_WPC;
  const float* A_T = ws + WS_AT;
  #pragma unroll
  for (int i = 0; i < 6; ++i) {        // stage Wpc[0..191][ow*64 .. +63]
    int idx = (i * 512 + t) * 4;       // 12288 floats
    int k = idx >> 6, ol = idx & 63;
    *reinterpret_cast<float4*>(&wp[idx]) =
        *reinterpret_cast<const float4*>(Wpc + (size_t)k * OUT_N + ow * 64 + ol);
  }
  __syncthreads();
  float acc[16];
  float bpv = bp[o];
  #pragma unroll
  for (int i = 0; i < 16; ++i) acc[i] = bpv;
  for (int k = 0; k < 192; ++k) {
    float wvv = wp[k * 64 + lane];                  // LDS, 2-way (free)
    const float* arow = A_T + (size_t)k * B_N + s0; // uniform -> s_load_dwordx16
    #pragma unroll
    for (int si = 0; si < 16; ++si)
      acc[si] = fmaf(arow[si], wvv, acc[si]);
  }
  #pragma unroll
  for (int si = 0; si < 16; ++si)
    out[(size_t)(s0 + si) * OUT_N + o] = acc[si];
}

extern "C" void kernel_launch(void* const* d_in, const int* in_sizes, int n_in,
                              void* d_out, int out_size, void* d_ws, size_t ws_size,
                              hipStream_t stream) {
  const float* x  = (const float*)d_in[0];
  const float* W1 = (const float*)d_in[1];
  const float* b1 = (const float*)d_in[2];
  const float* W2 = (const float*)d_in[3];
  const float* b2 = (const float*)d_in[4];
  const float* W3 = (const float*)d_in[5];
  // d_in[6] = b3 — unused by the reference
  const float* Wp = (const float*)d_in[7];
  const float* bp = (const float*)d_in[8];
  float* out = (float*)d_out;
  float* ws  = (float*)d_ws;

  hipLaunchKernelGGL(k_pre,     dim3(224), dim3(256), 0, stream, W1, W2, W3, ws);
  hipLaunchKernelGGL(k_wpc,     dim3(384), dim3(128), 0, stream, W1, W3, Wp, ws);
  hipLaunchKernelGGL(k_wpc_red, dim3(96),  dim3(256), 0, stream, ws);
  hipLaunchKernelGGL(k_h1,      dim3(256), dim3(512), 0, stream, x, W1, ws);
  hipLaunchKernelGGL(k_mid,     dim3(128), dim3(512), 0, stream, b1, b2, W2, ws);
  hipLaunchKernelGGL(k_out2,    dim3(512), dim3(512), 0, stream, bp, ws, out);
}

// Round 7
// 313.790 us; speedup vs baseline: 1.0285x; 1.0285x over previous
//
#include <hip/hip_runtime.h>

// DivergenceFreeMLP — all-f32 implementation.
// out = a2 @ Wp3 - c1 @ Wp1 + bp, where masks m1,m2 come from exact f32 h1,h2.
//   Wpc[192][512] = [W3^T Wp^T ; W1 Wp^T]  (precomputed per launch, 201M MACs)
//   A_T[192][8192] = [a2 ; -m1*c1] stored transposed (coalesced both sides)
// R6 PASS baseline; R7: k_h1 re-partitioned for occupancy — 1024 blocks of
// 128 thr (u-split-4 x k-split-2), 8 blocks/CU, 16 waves/CU (was 1 block/CU,
// 8 waves). Scalar-load serialization now hidden by 4 waves/SIMD TLP.
// Summation order per (u,s) unchanged -> bitwise-identical to R6 output.

#define B_N   8192
#define D_N   2048
#define H1_N  128
#define H2_N  64
#define OUT_N 512

// workspace layout (float offsets), peak 3,801,088 floats = 14.5 MiB
#define WS_W1R  0         // [128]
#define WS_W3C  128       // [64]
#define WS_W2T  256       // [128][64] -> 8448
#define WS_WPC  16384     // [192][512] -> 114688
#define WS_WPCP 114688    // [8][192][512] -> 901120 (dead after k_wpc_red)
#define WS_H1PA 131072    // [128][8192] -> 1179648 (aliases WPCP; lifetime disjoint)
#define WS_H1PB 1179648   // [128][8192] -> 2228224
#define WS_AT   2228224   // [192][8192] -> 3801088

__global__ __launch_bounds__(256) void k_pre(const float* __restrict__ W1,
                                             const float* __restrict__ W2,
                                             const float* __restrict__ W3,
                                             float* __restrict__ ws) {
  int b = blockIdx.x, t = threadIdx.x;
  __shared__ float red[256];
  if (b < 128) {                       // w1r[b] = sum_d W1[b][d]
    float s = 0.f;
    const float* row = W1 + (size_t)b * D_N;
    for (int i = t; i < D_N; i += 256) s += row[i];
    red[t] = s; __syncthreads();
    for (int off = 128; off > 0; off >>= 1) { if (t < off) red[t] += red[t + off]; __syncthreads(); }
    if (t == 0) ws[WS_W1R + b] = red[0];
  } else if (b < 192) {                // w3c[c] = sum_d W3[d][c]
    int c = b - 128;
    float s = 0.f;
    for (int d = t; d < D_N; d += 256) s += W3[(size_t)d * H2_N + c];
    red[t] = s; __syncthreads();
    for (int off = 128; off > 0; off >>= 1) { if (t < off) red[t] += red[t + off]; __syncthreads(); }
    if (t == 0) ws[WS_W3C + c] = red[0];
  } else {                             // W2T[j][u] = W2[u][j]
    int flat = (b - 192) * 256 + t;    // 0..8191
    int j = flat >> 6, u = flat & 63;
    ws[WS_W2T + j * H2_N + u] = W2[u * H1_N + j];
  }
}

// Wpc partials: block = (rt 0..5, ot 0..7, kc 0..7); tile 32r x 64o.
// K-chunk 256 processed as 4 sub-chunks of 64 (LDS tiles stride 68).
__global__ __launch_bounds__(128) void k_wpc(const float* __restrict__ W1,
                                             const float* __restrict__ W3,
                                             const float* __restrict__ Wp,
                                             float* __restrict__ ws) {
  int b = blockIdx.x, t = threadIdx.x;
  int rt = b % 6, ot = (b / 6) % 8, kc = b / 48;
  __shared__ float As[32 * 68];        // [r][k] stride 68, k-sub 64
  __shared__ float Bs[64 * 68];        // [o][k] stride 68
  int rg = t >> 4, og = t & 15;        // 8 x 16 thread grid, tile 4r x 4o
  float acc[4][4];
  #pragma unroll
  for (int i = 0; i < 4; ++i)
    #pragma unroll
    for (int j = 0; j < 4; ++j) acc[i][j] = 0.f;
  for (int sub = 0; sub < 4; ++sub) {
    int k0 = kc * 256 + sub * 64;
    __syncthreads();                   // protect prev-iter reads
    if (rt < 2) {  // rows r<64: A[r][k] = W3[k0+k][rt*32+r] (strided columns)
      #pragma unroll
      for (int i = 0; i < 4; ++i) {
        int flat = i * 128 + t;        // 512 float4: 8 rq x 64 kl
        int rq = flat & 7, kl = flat >> 3;
        const float4 v = *reinterpret_cast<const float4*>(W3 + (size_t)(k0 + kl) * H2_N + rt * 32 + rq * 4);
        As[(rq * 4 + 0) * 68 + kl] = v.x;
        As[(rq * 4 + 1) * 68 + kl] = v.y;
        As[(rq * 4 + 2) * 68 + kl] = v.z;
        As[(rq * 4 + 3) * 68 + kl] = v.w;
      }
    } else {       // rows r>=64: A[r][k] = W1[rt*32+r-64][k0+k]
      #pragma unroll
      for (int i = 0; i < 4; ++i) {
        int flat = i * 128 + t;        // 512 float4: 16 kq x 32 rl
        int kq = flat & 15, rl = flat >> 4;
        const float4 v = *reinterpret_cast<const float4*>(W1 + (size_t)(rt * 32 + rl - 64) * D_N + k0 + kq * 4);
        *reinterpret_cast<float4*>(&As[rl * 68 + kq * 4]) = v;
      }
    }
    #pragma unroll
    for (int i = 0; i < 8; ++i) {      // B[o][k] = Wp[ot*64+o][k0+k]
      int flat = i * 128 + t;          // 1024 float4: 16 kq x 64 ol
      int kq = flat & 15, ol = flat >> 4;
      const float4 v = *reinterpret_cast<const float4*>(Wp + (size_t)(ot * 64 + ol) * D_N + k0 + kq * 4);
      *reinterpret_cast<float4*>(&Bs[ol * 68 + kq * 4]) = v;
    }
    __syncthreads();
    for (int k = 0; k < 64; k += 4) {
      float4 a[4], bb[4];
      #pragma unroll
      for (int i = 0; i < 4; ++i) a[i] = *reinterpret_cast<const float4*>(&As[(rg * 4 + i) * 68 + k]);
      #pragma unroll
      for (int j = 0; j < 4; ++j) bb[j] = *reinterpret_cast<const float4*>(&Bs[(og * 4 + j) * 68 + k]);
      #pragma unroll
      for (int i = 0; i < 4; ++i)
        #pragma unroll
        for (int j = 0; j < 4; ++j) {
          acc[i][j] = fmaf(a[i].x, bb[j].x, acc[i][j]);
          acc[i][j] = fmaf(a[i].y, bb[j].y, acc[i][j]);
          acc[i][j] = fmaf(a[i].z, bb[j].z, acc[i][j]);
          acc[i][j] = fmaf(a[i].w, bb[j].w, acc[i][j]);
        }
    }
  }
  float* P = ws + WS_WPCP + (size_t)kc * (192 * 512);
  #pragma unroll
  for (int i = 0; i < 4; ++i) {
    int r = rt * 32 + rg * 4 + i;
    #pragma unroll
    for (int j = 0; j < 4; ++j)
      P[r * 512 + ot * 64 + og * 4 + j] = acc[i][j];
  }
}

__global__ __launch_bounds__(256) void k_wpc_red(float* __restrict__ ws) {
  int idx = (blockIdx.x * 256 + threadIdx.x) * 4;  // 96 blocks -> 98304 floats
  float4 s = make_float4(0.f, 0.f, 0.f, 0.f);
  #pragma unroll
  for (int p = 0; p < 8; ++p) {
    const float4 v = *reinterpret_cast<const float4*>(ws + WS_WPCP + (size_t)p * (192 * 512) + idx);
    s.x += v.x; s.y += v.y; s.z += v.z; s.w += v.w;
  }
  *reinterpret_cast<float4*>(ws + WS_WPC + idx) = s;
}

// h1 partial: grid 1024 = st(128) x ut(4) x kh(2); block 128 thr = 2 waves.
// Wave handles 16 units: u0 = ut*32 + wv*16. K-chunks of 64 within the k-half.
// 8 blocks/CU (LDS 16.6 KB) -> 16 waves/CU: TLP hides s_load serialization.
// Per-(u,s) k-summation order identical to R6 -> bitwise-same h1 partials.
__global__ __launch_bounds__(128) void k_h1(const float* __restrict__ x,
                                            const float* __restrict__ W1,
                                            float* __restrict__ ws) {
  __shared__ float xs[64 * 65];        // 16.6 KB, [k][65] transposed
  int b = blockIdx.x;                  // 1024 blocks
  int st = b >> 3, ut = (b >> 1) & 3, kh = b & 1;
  int s0 = st * 64;
  int t = threadIdx.x;
  int lane = t & 63;
  int wv = __builtin_amdgcn_readfirstlane(t >> 6);  // uniform wave id 0..1
  int u0 = ut * 32 + wv * 16;
  float acc[16];
  #pragma unroll
  for (int i = 0; i < 16; ++i) acc[i] = 0.f;
  for (int cc = 0; cc < 16; ++cc) {
    int kc = kh * 1024 + cc * 64;
    __syncthreads();
    #pragma unroll
    for (int r = 0; r < 8; ++r) {      // stage 64 samples x 64 k, transposed
      int flat = r * 128 + t;          // 1024 float4: kq = bits[3:0], s = bits[9:4]
      int kq = flat & 15;
      int s  = flat >> 4;
      const float4 v = *reinterpret_cast<const float4*>(x + (size_t)(s0 + s) * D_N + kc + kq * 4);
      xs[(kq * 4 + 0) * 65 + s] = v.x;  // bank = 4*kq + c + s mod 32 -> 2-way (free)
      xs[(kq * 4 + 1) * 65 + s] = v.y;
      xs[(kq * 4 + 2) * 65 + s] = v.z;
      xs[(kq * 4 + 3) * 65 + s] = v.w;
    }
    __syncthreads();
    const float* wbase = W1 + (size_t)u0 * D_N + kc;
    for (int k4 = 0; k4 < 64; k4 += 4) {
      float a0 = xs[(k4 + 0) * 65 + lane];
      float a1 = xs[(k4 + 1) * 65 + lane];
      float a2 = xs[(k4 + 2) * 65 + lane];
      float a3 = xs[(k4 + 3) * 65 + lane];
      #pragma unroll
      for (int uu = 0; uu < 16; ++uu) {
        const float* wr = wbase + (size_t)uu * D_N + k4;  // uniform -> s_load_dwordx4
        float c = acc[uu];
        c = fmaf(wr[0], a0, c);
        c = fmaf(wr[1], a1, c);
        c = fmaf(wr[2], a2, c);
        c = fmaf(wr[3], a3, c);
        acc[uu] = c;
      }
    }
  }
  float* hp = ws + (kh ? WS_H1PB : WS_H1PA);
  #pragma unroll
  for (int uu = 0; uu < 16; ++uu)
    hp[(size_t)(u0 + uu) * B_N + s0 + lane] = acc[uu];
}

// Fused mid stage: phase 1 computes h2, a2 (A_T rows 0..63) and sb=m2*w3c (LDS);
// phase 2 computes c1 and A_T rows 64..191 = -m1*c1. h1 = PA + PB + b1.
__global__ __launch_bounds__(512) void k_mid(const float* __restrict__ b1,
                                             const float* __restrict__ b2,
                                             const float* __restrict__ W2,
                                             float* __restrict__ ws) {
  __shared__ float hs[128 * 65];       // h1 + b1, 33.3 KB
  __shared__ float sb[64 * 65];        // m2*w3c,  16.6 KB
  int s0 = blockIdx.x * 64;            // 128 blocks
  int t = threadIdx.x;
  int lane = t & 63;
  int wv = __builtin_amdgcn_readfirstlane(t >> 6);  // 0..7
  const float* PA = ws + WS_H1PA;
  const float* PB = ws + WS_H1PB;
  const float* W2T = ws + WS_W2T;
  const float* w1r = ws + WS_W1R;
  const float* w3c = ws + WS_W3C;
  float* A_T = ws + WS_AT;
  // stage h1+b1: wave wv loads rows wv*16 .. wv*16+15
  #pragma unroll
  for (int jj = 0; jj < 16; ++jj) {
    int j = wv * 16 + jj;
    hs[j * 65 + lane] = PA[(size_t)j * B_N + s0 + lane]
                      + PB[(size_t)j * B_N + s0 + lane] + b1[j];
  }
  __syncthreads();
  // phase 1: wave wv owns u0 = wv*8 (8 units)
  {
    int u0 = wv * 8;
    float h2a[8], ta[8];
    #pragma unroll
    for (int i = 0; i < 8; ++i) { h2a[i] = b2[u0 + i]; ta[i] = 0.f; }
    for (int j = 0; j < H1_N; ++j) {
      float h = hs[j * 65 + lane];
      float g = fmaxf(h, 0.f);
      float a = (h > 0.f) ? w1r[j] : 0.f;
      const float* w2row = W2T + j * H2_N + u0;     // uniform -> s_load
      #pragma unroll
      for (int uu = 0; uu < 8; ++uu) {
        h2a[uu] = fmaf(w2row[uu], g, h2a[uu]);
        ta[uu]  = fmaf(w2row[uu], a, ta[uu]);
      }
    }
    #pragma unroll
    for (int uu = 0; uu < 8; ++uu) {
      bool m2 = h2a[uu] > 0.f;
      A_T[(size_t)(u0 + uu) * B_N + s0 + lane] = m2 ? ta[uu] : 0.f;
      sb[(u0 + uu) * 65 + lane] = m2 ? w3c[u0 + uu] : 0.f;
    }
  }
  __syncthreads();
  // phase 2: wave wv owns j0 = wv*16 (16 units)
  {
    int j0 = wv * 16;
    float c[16];
    #pragma unroll
    for (int i = 0; i < 16; ++i) c[i] = 0.f;
    for (int u = 0; u < H2_N; ++u) {
      float sv = sb[u * 65 + lane];
      const float* w2row = W2 + u * H1_N + j0;      // uniform -> s_load
      #pragma unroll
      for (int jj = 0; jj < 16; ++jj)
        c[jj] = fmaf(w2row[jj], sv, c[jj]);
    }
    #pragma unroll
    for (int jj = 0; jj < 16; ++jj) {
      float h = hs[(j0 + jj) * 65 + lane];
      A_T[(size_t)(64 + j0 + jj) * B_N + s0 + lane] = (h > 0.f) ? -c[jj] : 0.f;
    }
  }
}

// out[s][o] = bp[o] + sum_{k<192} A_T[k][s] * Wpc[k][o]
// block = 512 thr (8 waves x 16 samples = 128 samples), 64 o-cols; Wpc in LDS.
// grid 512 = 64 st8 x 8 ow.
__global__ __launch_bounds__(512) void k_out2(const float* __restrict__ bp,
                                              const float* __restrict__ ws,
                                              float* __restrict__ out) {
  __shared__ float wp[192 * 64];       // 48 KB
  int b = blockIdx.x;                  // 512 = 64 st8 x 8 ow
  int ow = b & 7, st8 = b >> 3;
  int t = threadIdx.x;
  int lane = t & 63;
  int wv = __builtin_amdgcn_readfirstlane(t >> 6);  // 0..7
  int s0 = st8 * 128 + wv * 16;
  int o = ow * 64 + lane;
  const float* Wpc = ws + WS_WPC;
  const float* A_T = ws + WS_AT;
  #pragma unroll
  for (int i = 0; i < 6; ++i) {        // stage Wpc[0..191][ow*64 .. +63]
    int idx = (i * 512 + t) * 4;       // 12288 floats
    int k = idx >> 6, ol = idx & 63;
    *reinterpret_cast<float4*>(&wp[idx]) =
        *reinterpret_cast<const float4*>(Wpc + (size_t)k * OUT_N + ow * 64 + ol);
  }
  __syncthreads();
  float acc[16];
  float bpv = bp[o];
  #pragma unroll
  for (int i = 0; i < 16; ++i) acc[i] = bpv;
  for (int k = 0; k < 192; ++k) {
    float wvv = wp[k * 64 + lane];                  // LDS, 2-way (free)
    const float* arow = A_T + (size_t)k * B_N + s0; // uniform -> s_load_dwordx16
    #pragma unroll
    for (int si = 0; si < 16; ++si)
      acc[si] = fmaf(arow[si], wvv, acc[si]);
  }
  #pragma unroll
  for (int si = 0; si < 16; ++si)
    out[(size_t)(s0 + si) * OUT_N + o] = acc[si];
}

extern "C" void kernel_launch(void* const* d_in, const int* in_sizes, int n_in,
                              void* d_out, int out_size, void* d_ws, size_t ws_size,
                              hipStream_t stream) {
  const float* x  = (const float*)d_in[0];
  const float* W1 = (const float*)d_in[1];
  const float* b1 = (const float*)d_in[2];
  const float* W2 = (const float*)d_in[3];
  const float* b2 = (const float*)d_in[4];
  const float* W3 = (const float*)d_in[5];
  // d_in[6] = b3 — unused by the reference
  const float* Wp = (const float*)d_in[7];
  const float* bp = (const float*)d_in[8];
  float* out = (float*)d_out;
  float* ws  = (float*)d_ws;

  hipLaunchKernelGGL(k_pre,     dim3(224),  dim3(256), 0, stream, W1, W2, W3, ws);
  hipLaunchKernelGGL(k_wpc,     dim3(384),  dim3(128), 0, stream, W1, W3, Wp, ws);
  hipLaunchKernelGGL(k_wpc_red, dim3(96),   dim3(256), 0, stream, ws);
  hipLaunchKernelGGL(k_h1,      dim3(1024), dim3(128), 0, stream, x, W1, ws);
  hipLaunchKernelGGL(k_mid,     dim3(128),  dim3(512), 0, stream, b1, b2, W2, ws);
  hipLaunchKernelGGL(k_out2,    dim3(512),  dim3(512), 0, stream, bp, ws, out);
}